// Round 9
// baseline (452.210 us; speedup 1.0000x reference)
//
#include <hip/hip_runtime.h>

#define B 8
#define NF 4096
#define NT 4096
#define D_HID 128
#define D_OUT 32
#define D_V 16
#define TILE_I 64

__device__ inline float fast_exp2(float x) {
#if __has_builtin(__builtin_amdgcn_exp2f)
  return __builtin_amdgcn_exp2f(x);
#else
  return exp2f(x);
#endif
}

// ---------------- MLP: [N,3] -> relu(x W1 + b1) W2 + b2 -> [N,32] ----------------
__global__ __launch_bounds__(64) void mlp_kernel(
    const float* __restrict__ x, const float* __restrict__ W1,
    const float* __restrict__ b1, const float* __restrict__ W2,
    const float* __restrict__ b2, float* __restrict__ out) {
  __shared__ float sW1[3 * D_HID];
  __shared__ float sb1[D_HID];
  __shared__ float sW2[D_HID * D_OUT];
  __shared__ float sb2[D_OUT];
  const int tid = threadIdx.x;
  for (int idx = tid; idx < D_HID * D_OUT; idx += 64) sW2[idx] = W2[idx];
  for (int idx = tid; idx < 3 * D_HID; idx += 64) sW1[idx] = W1[idx];
  for (int idx = tid; idx < D_HID; idx += 64) sb1[idx] = b1[idx];
  if (tid < D_OUT) sb2[tid] = b2[tid];
  __syncthreads();

  const int t = blockIdx.x * 64 + tid;
  const float x0 = x[t * 3 + 0];
  const float x1 = x[t * 3 + 1];
  const float x2 = x[t * 3 + 2];
  float acc[D_OUT];
#pragma unroll
  for (int o = 0; o < D_OUT; ++o) acc[o] = sb2[o];
#pragma unroll 4
  for (int h = 0; h < D_HID; ++h) {
    float hv = fmaf(x2, sW1[2 * D_HID + h],
               fmaf(x1, sW1[1 * D_HID + h],
               fmaf(x0, sW1[0 * D_HID + h], sb1[h])));
    hv = fmaxf(hv, 0.0f);
    const float4* w2r = reinterpret_cast<const float4*>(&sW2[h * D_OUT]);
#pragma unroll
    for (int o4 = 0; o4 < D_OUT / 4; ++o4) {
      const float4 w = w2r[o4];
      acc[o4 * 4 + 0] = fmaf(hv, w.x, acc[o4 * 4 + 0]);
      acc[o4 * 4 + 1] = fmaf(hv, w.y, acc[o4 * 4 + 1]);
      acc[o4 * 4 + 2] = fmaf(hv, w.z, acc[o4 * 4 + 2]);
      acc[o4 * 4 + 3] = fmaf(hv, w.w, acc[o4 * 4 + 3]);
    }
  }
  float* op = out + (size_t)t * D_OUT;
#pragma unroll
  for (int o = 0; o < D_OUT; o += 4) {
    float4 w = make_float4(acc[o], acc[o + 1], acc[o + 2], acc[o + 3]);
    *reinterpret_cast<float4*>(op + o) = w;
  }
}

// ------------- fused L1-dist + softmax(over i) + PV, flash style over NF -------------
// Lane-pair D-split: even lanes own dims 0..15 / V[0:8], odd own dims 16..31 / V[8:16].
// One shfl_xor(1) merges the L1 partial (bit-exact). 4 j-columns per pair at 168 VGPR.
// LDS per row: 4 K + 2 V ds_read_b128 (two-group broadcast) + 4 b32 swizzles.
// Waves start the 64-row tile at offset waveid*16 (stagger -> decorrelated pipe bursts).
__global__ __launch_bounds__(256, 3) void attn_kernel(
    const float* __restrict__ Wk, const float* __restrict__ Wq,
    const float* __restrict__ Vf, float* __restrict__ partial,
    int nchunks, int chlen) {
  // per buffer: K tile 64x32 = 512 float4, V tile 64x16 = 256 float4 -> 12 KB
  __shared__ float4 sTile[2][768];
  const int tid = threadIdx.x;
  const int pair = tid >> 1;
  const int par = tid & 1;           // D-half owned by this lane
  const int wv = tid >> 6;           // wave id 0..3
  const int b = blockIdx.y;
  const int c = blockIdx.z;
  const int i0 = c * chlen;
  const int ntiles = chlen / TILE_I;
  const int jbase = blockIdx.x * 512 + pair;  // column = jbase + s*128

  constexpr float C2 = -0.72134752044448170368f;  // -log2(e)/2

  // q: this lane's 16-dim half for 4 columns (pair-coalesced 128B loads)
  float q[4][16];
#pragma unroll
  for (int s = 0; s < 4; ++s) {
    const float* qp = Wq + ((size_t)b * NT + jbase + s * 128) * D_OUT + par * 16;
#pragma unroll
    for (int d4 = 0; d4 < 4; ++d4) {
      float4 t4 = *reinterpret_cast<const float4*>(qp + d4 * 4);
      q[s][d4 * 4 + 0] = t4.x;
      q[s][d4 * 4 + 1] = t4.y;
      q[s][d4 * 4 + 2] = t4.z;
      q[s][d4 * 4 + 3] = t4.w;
    }
  }

  float m[4], l[4], acc[4][8];
#pragma unroll
  for (int s = 0; s < 4; ++s) {
    m[s] = -1e30f;  // log2 domain; first row self-normalizes
    l[s] = 0.0f;
#pragma unroll
    for (int k = 0; k < 8; ++k) acc[s][k] = 0.0f;
  }

  const float4* gK4 = reinterpret_cast<const float4*>(Wk + ((size_t)b * NF + i0) * D_OUT);
  const float4* gV4 = reinterpret_cast<const float4*>(Vf + ((size_t)b * NF + i0) * D_V);

  // prologue: stage tile 0 into buf 0
  {
    float4 f0 = gK4[tid];
    float4 f1 = gK4[256 + tid];
    float4 f2 = gV4[tid];
    sTile[0][tid] = f0;
    sTile[0][256 + tid] = f1;
    sTile[0][512 + tid] = f2;
  }
  __syncthreads();

  for (int t = 0; t < ntiles; ++t) {
    const int cur = t & 1;
    float4 f0, f1, f2;
    const bool more = (t + 1 < ntiles);
    if (more) {  // issue next tile's loads; they fly during the 64-row compute
      f0 = gK4[(size_t)(t + 1) * 512 + tid];
      f1 = gK4[(size_t)(t + 1) * 512 + 256 + tid];
      f2 = gV4[(size_t)(t + 1) * 256 + tid];
    }
    for (int rr = 0; rr < TILE_I; ++rr) {
      const int r = (rr + (wv << 4)) & (TILE_I - 1);  // per-wave stagger
      const float4* kp = &sTile[cur][r * 8 + par * 4];
      const float4 k0 = kp[0];
      const float4 k1 = kp[1];
      const float4 k2 = kp[2];
      const float4 k3 = kp[3];

      // L1 partial over this lane's 16 dims, 4 slots x 2 chains
      float pa[4];
#pragma unroll
      for (int s = 0; s < 4; ++s) {
        float A = fabsf(k0.x - q[s][0]);
        float Bb = fabsf(k0.y - q[s][1]);
        A += fabsf(k0.z - q[s][2]);
        Bb += fabsf(k0.w - q[s][3]);
        A += fabsf(k1.x - q[s][4]);
        Bb += fabsf(k1.y - q[s][5]);
        A += fabsf(k1.z - q[s][6]);
        Bb += fabsf(k1.w - q[s][7]);
        A += fabsf(k2.x - q[s][8]);
        Bb += fabsf(k2.y - q[s][9]);
        A += fabsf(k2.z - q[s][10]);
        Bb += fabsf(k2.w - q[s][11]);
        A += fabsf(k3.x - q[s][12]);
        Bb += fabsf(k3.y - q[s][13]);
        A += fabsf(k3.z - q[s][14]);
        Bb += fabsf(k3.w - q[s][15]);
        pa[s] = A + Bb;
      }

      // merge halves across the lane pair (IEEE add commutes -> bit-identical)
      float s2[4], parg[4];
#pragma unroll
      for (int s = 0; s < 4; ++s) {
        const float dist = pa[s] + __shfl_xor(pa[s], 1);
        s2[s] = C2 * (dist * dist);
        parg[s] = s2[s] - m[s];
      }
      const float mparg = fmaxf(fmaxf(parg[0], parg[1]), fmaxf(parg[2], parg[3]));
      if (__any(mparg > 4.0f)) {  // rare, wave-uniform rescale
#pragma unroll
        for (int s = 0; s < 4; ++s) {
          const float mn = fmaxf(m[s], s2[s]);
          const float al = fast_exp2(m[s] - mn);
          l[s] *= al;
#pragma unroll
          for (int k = 0; k < 8; ++k) acc[s][k] *= al;
          m[s] = mn;
          parg[s] = s2[s] - mn;
        }
      }
      float p[4];
#pragma unroll
      for (int s = 0; s < 4; ++s) {
        p[s] = fast_exp2(parg[s]);
        l[s] += p[s];
      }

      // this lane's V half
      const float4* vp = &sTile[cur][512 + r * 4 + par * 2];
      const float4 v0 = vp[0];
      const float4 v1 = vp[1];
#pragma unroll
      for (int s = 0; s < 4; ++s) {
        acc[s][0] = fmaf(p[s], v0.x, acc[s][0]);
        acc[s][1] = fmaf(p[s], v0.y, acc[s][1]);
        acc[s][2] = fmaf(p[s], v0.z, acc[s][2]);
        acc[s][3] = fmaf(p[s], v0.w, acc[s][3]);
        acc[s][4] = fmaf(p[s], v1.x, acc[s][4]);
        acc[s][5] = fmaf(p[s], v1.y, acc[s][5]);
        acc[s][6] = fmaf(p[s], v1.z, acc[s][6]);
        acc[s][7] = fmaf(p[s], v1.w, acc[s][7]);
      }
    }
    if (more) {  // write-late: loads long since landed
      const int nxt = cur ^ 1;
      sTile[nxt][tid] = f0;
      sTile[nxt][256 + tid] = f1;
      sTile[nxt][512 + tid] = f2;
    }
    __syncthreads();
  }

  // SoA partials: field f at partial[f*fstride + (c*B+b)*NT + j]; even lane writes
  // m,l and V-fields 0..7, odd lane V-fields 8..15.
  const size_t fstride = (size_t)nchunks * B * NT;
  const size_t base = ((size_t)c * B + b) * NT;
#pragma unroll
  for (int s = 0; s < 4; ++s) {
    float* ps = partial + base + (jbase + s * 128);
    if (par == 0) {
      ps[0] = m[s];
      ps[fstride] = l[s];
    }
#pragma unroll
    for (int k = 0; k < 8; ++k)
      ps[(size_t)(2 + par * 8 + k) * fstride] = acc[s][k];
  }
}

// ---------------- combine NF-chunk partials -> output ----------------
__global__ __launch_bounds__(256) void combine_kernel(
    const float* __restrict__ partial, float* __restrict__ out, int nchunks) {
  const int t = blockIdx.x * 256 + threadIdx.x;  // = b*NT + j
  const size_t fstride = (size_t)nchunks * B * NT;
  float M = -1e30f;
  for (int c = 0; c < nchunks; ++c)
    M = fmaxf(M, partial[(size_t)c * (B * NT) + t]);
  float L = 0.0f;
  float acc[D_V];
#pragma unroll
  for (int k = 0; k < D_V; ++k) acc[k] = 0.0f;
  for (int c = 0; c < nchunks; ++c) {
    const size_t base = (size_t)c * (B * NT) + t;
    const float w = fast_exp2(partial[base] - M);
    L = fmaf(w, partial[fstride + base], L);
#pragma unroll
    for (int k = 0; k < D_V; ++k)
      acc[k] = fmaf(w, partial[(size_t)(2 + k) * fstride + base], acc[k]);
  }
  const float inv = 1.0f / L;
  float* op = out + (size_t)t * D_V;
#pragma unroll
  for (int k = 0; k < D_V; ++k) op[k] = acc[k] * inv;
}

extern "C" void kernel_launch(void* const* d_in, const int* in_sizes, int n_in,
                              void* d_out, int out_size, void* d_ws, size_t ws_size,
                              hipStream_t stream) {
  const float* coords_f = (const float*)d_in[0];
  const float* values_f = (const float*)d_in[1];
  const float* coords_t = (const float*)d_in[2];
  const float* Wk1 = (const float*)d_in[3];
  const float* bk1 = (const float*)d_in[4];
  const float* Wk2 = (const float*)d_in[5];
  const float* bk2 = (const float*)d_in[6];
  const float* Wq1 = (const float*)d_in[7];
  const float* bq1 = (const float*)d_in[8];
  const float* Wq2 = (const float*)d_in[9];
  const float* bq2 = (const float*)d_in[10];
  float* out = (float*)d_out;

  float* Wk = (float*)d_ws;                        // 4 MB
  float* Wq = Wk + (size_t)B * NF * D_OUT;         // 4 MB
  float* partial = Wq + (size_t)B * NT * D_OUT;

  const size_t fixed = (size_t)(B * NF * D_OUT + B * NT * D_OUT) * sizeof(float);
  int nchunks = 32;  // chlen = 128 = 2 tiles of 64
  while (nchunks > 1 &&
         fixed + (size_t)B * NT * nchunks * 18 * sizeof(float) > ws_size)
    nchunks >>= 1;
  const int chlen = NF / nchunks;

  hipLaunchKernelGGL(mlp_kernel, dim3(B * NF / 64), dim3(64), 0, stream,
                     coords_f, Wk1, bk1, Wk2, bk2, Wk);
  hipLaunchKernelGGL(mlp_kernel, dim3(B * NT / 64), dim3(64), 0, stream,
                     coords_t, Wq1, bq1, Wq2, bq2, Wq);
  hipLaunchKernelGGL(attn_kernel, dim3(NT / 512, B, nchunks), dim3(256), 0, stream,
                     Wk, Wq, values_f, partial, nchunks, chlen);
  hipLaunchKernelGGL(combine_kernel, dim3(B * NT / 256), dim3(256), 0, stream,
                     partial, out, nchunks);
}